// Round 1
// baseline (161.864 us; speedup 1.0000x reference)
//
#include <hip/hip_runtime.h>
#include <math.h>

#define T_LEN   8192
#define TP_LEN  8129   // T - L + 1
#define EPSF    1e-6f

// ---------------------------------------------------------------------------
// Kernel 1: znorm the 64 shapelets (P=64, C=1, L=64), store transposed
// snT[l*64 + p], plus per-shapelet sum (≈0) and sum-of-squares (≈64).
// ---------------------------------------------------------------------------
__global__ __launch_bounds__(64) void prep_kernel(const float* __restrict__ sh,
                                                  float* __restrict__ snT,
                                                  float* __restrict__ snsum,
                                                  float* __restrict__ s2) {
    int p = threadIdx.x;   // one thread per shapelet
    float v[64];
    float s1 = 0.f;
#pragma unroll
    for (int l = 0; l < 64; ++l) { v[l] = sh[p * 64 + l]; s1 += v[l]; }
    float mu = s1 * (1.f / 64.f);
    float sq = 0.f;
#pragma unroll
    for (int l = 0; l < 64; ++l) { float d = v[l] - mu; sq = fmaf(d, d, sq); }
    float var = sq * (1.f / 64.f);
    float sd  = fmaxf(sqrtf(var), EPSF);
    float inv = 1.f / sd;
    float ssum = 0.f, ss2 = 0.f;
#pragma unroll
    for (int l = 0; l < 64; ++l) {
        float s = (v[l] - mu) * inv;
        snT[l * 64 + p] = s;
        ssum += s;
        ss2  = fmaf(s, s, ss2);
    }
    snsum[p] = ssum;
    s2[p]    = ss2;
}

// ---------------------------------------------------------------------------
// Kernel 2: one block = one (batch b, 64-row tile of output t).
// Output row t maps to window tp = t - 32 (valid iff 0 <= tp < 8129);
// invalid rows get zeros (this covers the reference's zero padding).
// dot[t,p] = (sum_l x[tp+l]*sn[p,l] - mu_t * snsum[p]) / sd_t
// dist2    = w2_t + s2[p] - 2*dot ;  act = exp(-dist2)
// Per-thread register tile: 4 t x 4 p. x values slide through registers.
// ---------------------------------------------------------------------------
__global__ __launch_bounds__(256) void shapelet_kernel(
        const float* __restrict__ x,
        const float* __restrict__ snT,
        const float* __restrict__ snsum,
        const float* __restrict__ s2,
        float* __restrict__ out) {
    __shared__ float lsn[64 * 64];   // [l][p], 16 KB
    __shared__ float xs[128];        // x[t0-32 + i], i in [0,127]
    __shared__ float lmu[64], linv[64], lw2[64], ls2[64], lsum[64];

    const int tid  = threadIdx.x;
    const int tile = blockIdx.x & 127;     // 128 t-tiles of 64
    const int b    = blockIdx.x >> 7;      // 32 batches
    const int t0   = tile << 6;

    // ---- stage shapelets (coalesced float4) ----
    const float4* g4 = (const float4*)snT;
    float4* l4 = (float4*)lsn;
#pragma unroll
    for (int i = 0; i < 4; ++i) l4[tid + i * 256] = g4[tid + i * 256];

    // ---- stage x tile (127 used values; load 128 with edge guard) ----
    if (tid < 128) {
        int g = t0 - 32 + tid;
        xs[tid] = ((unsigned)g < (unsigned)T_LEN) ? x[b * T_LEN + g] : 0.f;
    }
    if (tid >= 128 && tid < 192) {
        int p = tid - 128;
        ls2[p]  = s2[p];
        lsum[p] = snsum[p];
    }
    __syncthreads();

    // ---- per-window stats (threads 0..63, one per tile row) ----
    if (tid < 64) {
        float s1 = 0.f, sq = 0.f;
#pragma unroll
        for (int l = 0; l < 64; ++l) {
            float v = xs[tid + l];
            s1 += v;
            sq = fmaf(v, v, sq);
        }
        float mu  = s1 * (1.f / 64.f);
        float var = fmaxf(sq * (1.f / 64.f) - mu * mu, 0.f);
        float sd  = fmaxf(sqrtf(var), EPSF);
        lmu[tid]  = mu;
        linv[tid] = 1.f / sd;
        lw2[tid]  = 64.f * var / (sd * sd);
    }
    __syncthreads();

    // ---- main correlation: 4t x 4p per thread ----
    const int tx = tid & 15;        // p group: p = tx*4 + j
    const int ty = tid >> 4;        // t group: r = ty*4 + i
    const int rbase = ty << 2;

    float acc[4][4];
#pragma unroll
    for (int i = 0; i < 4; ++i)
#pragma unroll
        for (int j = 0; j < 4; ++j) acc[i][j] = 0.f;

    float a0 = xs[rbase + 0];
    float a1 = xs[rbase + 1];
    float a2 = xs[rbase + 2];
    float a3 = xs[rbase + 3];

#pragma unroll
    for (int l = 0; l < 64; ++l) {
        const float4 bb = *(const float4*)&lsn[(l << 6) + (tx << 2)];
        acc[0][0] = fmaf(a0, bb.x, acc[0][0]);
        acc[0][1] = fmaf(a0, bb.y, acc[0][1]);
        acc[0][2] = fmaf(a0, bb.z, acc[0][2]);
        acc[0][3] = fmaf(a0, bb.w, acc[0][3]);
        acc[1][0] = fmaf(a1, bb.x, acc[1][0]);
        acc[1][1] = fmaf(a1, bb.y, acc[1][1]);
        acc[1][2] = fmaf(a1, bb.z, acc[1][2]);
        acc[1][3] = fmaf(a1, bb.w, acc[1][3]);
        acc[2][0] = fmaf(a2, bb.x, acc[2][0]);
        acc[2][1] = fmaf(a2, bb.y, acc[2][1]);
        acc[2][2] = fmaf(a2, bb.z, acc[2][2]);
        acc[2][3] = fmaf(a2, bb.w, acc[2][3]);
        acc[3][0] = fmaf(a3, bb.x, acc[3][0]);
        acc[3][1] = fmaf(a3, bb.y, acc[3][1]);
        acc[3][2] = fmaf(a3, bb.z, acc[3][2]);
        acc[3][3] = fmaf(a3, bb.w, acc[3][3]);
        // slide window by one
        a0 = a1; a1 = a2; a2 = a3;
        a3 = xs[rbase + l + 4];   // max index 60+63+4 = 127, in bounds
    }

    // ---- epilogue: fold znorm, exp, store (covers zero padding) ----
#pragma unroll
    for (int i = 0; i < 4; ++i) {
        const int r  = rbase + i;
        const int t  = t0 + r;
        const int tp = t - 32;
        const bool valid = (tp >= 0) && (tp < TP_LEN);
        const float mu  = lmu[r];
        const float inv = linv[r];
        const float w2  = lw2[r];
        float4 o;
        {
            const int p0 = tx << 2;
            float d0 = (acc[i][0] - mu * lsum[p0 + 0]) * inv;
            float d1 = (acc[i][1] - mu * lsum[p0 + 1]) * inv;
            float d2 = (acc[i][2] - mu * lsum[p0 + 2]) * inv;
            float d3 = (acc[i][3] - mu * lsum[p0 + 3]) * inv;
            float e0 = w2 + ls2[p0 + 0] - 2.f * d0;
            float e1 = w2 + ls2[p0 + 1] - 2.f * d1;
            float e2 = w2 + ls2[p0 + 2] - 2.f * d2;
            float e3 = w2 + ls2[p0 + 3] - 2.f * d3;
            o.x = valid ? __expf(-e0) : 0.f;
            o.y = valid ? __expf(-e1) : 0.f;
            o.z = valid ? __expf(-e2) : 0.f;
            o.w = valid ? __expf(-e3) : 0.f;
        }
        *(float4*)&out[((size_t)(b * T_LEN + t) << 6) + (tx << 2)] = o;
    }
}

extern "C" void kernel_launch(void* const* d_in, const int* in_sizes, int n_in,
                              void* d_out, int out_size, void* d_ws, size_t ws_size,
                              hipStream_t stream) {
    const float* x  = (const float*)d_in[0];   // (32, 8192, 1)
    const float* sh = (const float*)d_in[1];   // (64, 1, 64)
    float* out = (float*)d_out;                // (32, 8192, 64)

    float* snT   = (float*)d_ws;               // 64*64 floats
    float* snsum = snT + 64 * 64;              // 64 floats
    float* s2v   = snsum + 64;                 // 64 floats

    prep_kernel<<<1, 64, 0, stream>>>(sh, snT, snsum, s2v);
    shapelet_kernel<<<32 * 128, 256, 0, stream>>>(x, snT, snsum, s2v, out);
}

// Round 2
// 86.472 us; speedup vs baseline: 1.8719x; 1.8719x over previous
//
#include <hip/hip_runtime.h>
#include <math.h>

#define T_LEN 8192
#define EPSF  1e-6f

typedef __attribute__((ext_vector_type(8))) short short8;
typedef __attribute__((ext_vector_type(4))) float float4v;

// ---------------------------------------------------------------------------
// Kernel 1: znorm shapelets (P=64, L=64), split each value into bf16 hi + lo
// (hi = truncated top 16 bits, lo = bf16(residual)); also per-shapelet sum and
// sum-of-squares computed from the RECONSTRUCTED (hi+lo) values so the
// epilogue correction matches what the MFMA actually dots against.
// Layout: bhi[p*64 + l], blo[p*64 + l]  (row-major per shapelet = B^T,
// which is exactly the MFMA B-operand's per-lane contiguous-k order).
// ---------------------------------------------------------------------------
__global__ __launch_bounds__(64) void prep_kernel(const float* __restrict__ sh,
                                                  unsigned short* __restrict__ bhi,
                                                  unsigned short* __restrict__ blo,
                                                  float* __restrict__ snsum,
                                                  float* __restrict__ s2) {
    int p = threadIdx.x;
    float v[64];
    float s1 = 0.f;
#pragma unroll
    for (int l = 0; l < 64; ++l) { v[l] = sh[p * 64 + l]; s1 += v[l]; }
    float mu = s1 * (1.f / 64.f);
    float sq = 0.f;
#pragma unroll
    for (int l = 0; l < 64; ++l) { float d = v[l] - mu; sq = fmaf(d, d, sq); }
    float sd  = fmaxf(sqrtf(sq * (1.f / 64.f)), EPSF);
    float inv = 1.f / sd;
    float ssum = 0.f, ss2 = 0.f;
#pragma unroll
    for (int l = 0; l < 64; ++l) {
        float s = (v[l] - mu) * inv;
        unsigned ub = __float_as_uint(s);
        unsigned hb = ub & 0xFFFF0000u;
        float hi = __uint_as_float(hb);
        float lo = s - hi;
        unsigned lb = __float_as_uint(lo) & 0xFFFF0000u;
        bhi[p * 64 + l] = (unsigned short)(ub >> 16);
        blo[p * 64 + l] = (unsigned short)(__float_as_uint(lo) >> 16);
        float eff = hi + __uint_as_float(lb);   // what the MFMA effectively sees
        ssum += eff;
        ss2  = fmaf(eff, eff, ss2);
    }
    snsum[p] = ssum;
    s2[p]    = ss2;
}

// ---------------------------------------------------------------------------
// Kernel 2: one block = (batch b, 128-row t-strip). 4 waves; wave w owns
// 16-row sub-strips. Two 64-row units per block; B fragments register-cached.
// dot via 3-MFMA bf16 hi/lo split (hi*hi + hi*lo + lo*hi), fp32 accumulate.
// Window znorm folds to per-row (mu, 1/sd, w2) applied in the epilogue.
// Rows t<32 or t>8160 are the reference's zero padding.
// ---------------------------------------------------------------------------
__global__ __launch_bounds__(256, 3) void shapelet_mfma(
        const float* __restrict__ x,
        const unsigned short* __restrict__ gbhi,
        const unsigned short* __restrict__ gblo,
        const float* __restrict__ gsum,
        const float* __restrict__ gs2,
        float* __restrict__ out) {
    // 72-short rows: 144 B = 9*16 B -> float4-aligned every row, and the
    // b128 frag read hits banks 2-way (free).
    __shared__ unsigned short Bhi[64][72];
    __shared__ unsigned short Blo[64][72];
    __shared__ float xs[192];                    // x[t0-32 .. t0+159]
    __shared__ float lmu[128], linv[128], lw2[128];
    __shared__ float lsum[64], ls2[64];

    const int tid  = threadIdx.x;
    const int lane = tid & 63;
    const int wave = tid >> 6;
    const int n    = lane & 15;
    const int quad = lane >> 4;

    const int super = blockIdx.x & 63;           // 64 strips of 128 rows
    const int b     = blockIdx.x >> 6;           // 32 batches
    const int t0    = super << 7;

    // ---- stage B hi/lo (global float4 -> LDS float4, both 16B-aligned) ----
    const float4* gh4 = (const float4*)gbhi;     // 512 float4 = 4096 shorts
    const float4* gl4 = (const float4*)gblo;
#pragma unroll
    for (int i = 0; i < 2; ++i) {
        int idx = tid + (i << 8);
        int p = idx >> 3, k0 = (idx & 7) << 3;
        *(float4*)&Bhi[p][k0] = gh4[idx];
        *(float4*)&Blo[p][k0] = gl4[idx];
    }
    if (tid < 64) { lsum[tid] = gsum[tid]; ls2[tid] = gs2[tid]; }
    if (tid < 192) {
        int g = t0 - 32 + tid;
        xs[tid] = ((unsigned)g < (unsigned)T_LEN) ? x[(size_t)b * T_LEN + g] : 0.f;
    }
    __syncthreads();

    // ---- B fragments -> registers (reused across both units) ----
    // B-operand layout: lane holds B[k = quad*8+j + 32*h][n_col = lane&15];
    // n_col = shapelet p, contiguous k = contiguous l in bhi[p][*].
    short8 Bh[4][2], Bl[4][2];
#pragma unroll
    for (int pt = 0; pt < 4; ++pt)
#pragma unroll
        for (int h = 0; h < 2; ++h) {
            Bh[pt][h] = *(const short8*)&Bhi[pt * 16 + n][h * 32 + (quad << 3)];
            Bl[pt][h] = *(const short8*)&Blo[pt * 16 + n][h * 32 + (quad << 3)];
        }

    // ---- per-row window stats (rows 0..127; waves 2,3 already did B) ----
    if (tid < 128) {
        float s1 = 0.f, sq = 0.f;
#pragma unroll
        for (int l = 0; l < 64; ++l) { float v = xs[tid + l]; s1 += v; sq = fmaf(v, v, sq); }
        float mu  = s1 * (1.f / 64.f);
        float var = fmaxf(sq * (1.f / 64.f) - mu * mu, 0.f);
        float sd  = fmaxf(sqrtf(var), EPSF);
        float inv = 1.f / sd;
        lmu[tid]  = mu;
        linv[tid] = inv;
        lw2[tid]  = 64.f * var * inv * inv;
    }
    __syncthreads();

#pragma unroll
    for (int u = 0; u < 2; ++u) {
        // ---- A fragments: A[m][k] = xs[u*64 + wave*16 + m + k] ----
        // A-operand layout: lane holds A[m = lane&15][k = quad*8+j + 32*h]
        const int abase = (u << 6) + (wave << 4) + n + (quad << 3);
        short8 Ah[2], Al[2];
#pragma unroll
        for (int h = 0; h < 2; ++h) {
#pragma unroll
            for (int j = 0; j < 8; ++j) {
                float v = xs[abase + h * 32 + j];
                unsigned ub = __float_as_uint(v);
                unsigned hb = ub & 0xFFFF0000u;
                float lo = v - __uint_as_float(hb);
                Ah[h][j] = (short)(ub >> 16);
                Al[h][j] = (short)(__float_as_uint(lo) >> 16);
            }
        }

        float4v acc[4];
#pragma unroll
        for (int pt = 0; pt < 4; ++pt) {
            float4v a = {0.f, 0.f, 0.f, 0.f};
#pragma unroll
            for (int h = 0; h < 2; ++h) {
                a = __builtin_amdgcn_mfma_f32_16x16x32_bf16(Ah[h], Bh[pt][h], a, 0, 0, 0);
                a = __builtin_amdgcn_mfma_f32_16x16x32_bf16(Ah[h], Bl[pt][h], a, 0, 0, 0);
                a = __builtin_amdgcn_mfma_f32_16x16x32_bf16(Al[h], Bh[pt][h], a, 0, 0, 0);
            }
            acc[pt] = a;
        }

        // ---- epilogue: fold znorm, exp, store ----
        float sm[4], sv[4];
#pragma unroll
        for (int pt = 0; pt < 4; ++pt) { sm[pt] = lsum[pt * 16 + n]; sv[pt] = ls2[pt * 16 + n]; }
#pragma unroll
        for (int r = 0; r < 4; ++r) {
            // C/D layout: col = lane&15, row = quad*4 + r
            int tl = (u << 6) + (wave << 4) + (quad << 2) + r;
            int tg = t0 + tl;
            bool valid = (tg >= 32) && (tg <= 8160);
            float mu  = lmu[tl];
            float inv = linv[tl];
            float w2  = lw2[tl];
            float* orow = out + ((size_t)(b * T_LEN + tg) << 6);
#pragma unroll
            for (int pt = 0; pt < 4; ++pt) {
                float dot  = (acc[pt][r] - mu * sm[pt]) * inv;
                float dist = w2 + sv[pt] - 2.f * dot;
                orow[pt * 16 + n] = valid ? __expf(-dist) : 0.f;
            }
        }
    }
}

extern "C" void kernel_launch(void* const* d_in, const int* in_sizes, int n_in,
                              void* d_out, int out_size, void* d_ws, size_t ws_size,
                              hipStream_t stream) {
    const float* x  = (const float*)d_in[0];   // (32, 8192, 1)
    const float* sh = (const float*)d_in[1];   // (64, 1, 64)
    float* out = (float*)d_out;                // (32, 8192, 64)

    unsigned short* bhi = (unsigned short*)d_ws;          // 4096 shorts
    unsigned short* blo = bhi + 64 * 64;                  // 4096 shorts
    float* snsum = (float*)(blo + 64 * 64);               // 64 floats
    float* s2v   = snsum + 64;                            // 64 floats

    prep_kernel<<<1, 64, 0, stream>>>(sh, bhi, blo, snsum, s2v);
    shapelet_mfma<<<32 * 64, 256, 0, stream>>>(x, bhi, blo, snsum, s2v, out);
}

// Round 4
// 85.234 us; speedup vs baseline: 1.8991x; 1.0145x over previous
//
#include <hip/hip_runtime.h>
#include <math.h>

#define T_LEN 8192
#define EPSF  1e-6f

typedef __attribute__((ext_vector_type(8))) short short8;
typedef __attribute__((ext_vector_type(4))) float float4v;

// ---------------------------------------------------------------------------
// Single fused kernel. One block = (batch b, 128-row t-strip), 2048 blocks.
//
// Phase 0: stage raw shapelets (16 KB, coalesced float4) -> Sraw LDS;
//          stage x window (192 floats) -> xs LDS.
// Phase 1: threads 0-63: one thread per shapelet, SERIAL two-pass znorm +
//          bf16 hi/lo split — arithmetic expression-for-expression identical
//          to the R2 prep kernel (which passed with 99x margin), so the
//          staged Bhi/Blo/lsum/ls2 are bit-identical to R2's.
//          Threads 64-191: per-output-row window stats (mu, 1/sd, w2).
// Phase 2: B fragments -> registers; 3-MFMA bf16 hi/lo GEMM
//          (hi*hi + hi*lo + lo*hi, fp32 accum); epilogue folds the window
//          znorm, exp, store. Rows t<32 / t>8160 are the zero padding.
// ---------------------------------------------------------------------------
__global__ __launch_bounds__(256, 4) void shapelet_fused(
        const float* __restrict__ x,
        const float* __restrict__ sh,
        float* __restrict__ out) {
    __shared__ float Sraw[64][65];                 // +1 pad: serial row reads 2-way
    __shared__ unsigned short Bhi[64][72];         // 144 B rows: 16B-aligned
    __shared__ unsigned short Blo[64][72];
    __shared__ float xs[192];                      // x[t0-32 .. t0+159]
    __shared__ float lmu[128], linv[128], lw2[128];
    __shared__ float lsum[64], ls2[64];

    const int tid  = threadIdx.x;
    const int lane = tid & 63;
    const int wave = tid >> 6;
    const int n    = lane & 15;
    const int quad = lane >> 4;

    const int super = blockIdx.x & 63;             // 64 strips of 128 rows
    const int b     = blockIdx.x >> 6;             // 32 batches
    const int t0    = super << 7;

    // ---------------- phase 0: staging ----------------
    {
        const float4* g4 = (const float4*)sh;      // 1024 float4 = 4096 floats
#pragma unroll
        for (int i = 0; i < 4; ++i) {
            int idx = tid + (i << 8);
            float4 v = g4[idx];
            int e = idx << 2;
            int row = e >> 6, col = e & 63;
            Sraw[row][col + 0] = v.x;
            Sraw[row][col + 1] = v.y;
            Sraw[row][col + 2] = v.z;
            Sraw[row][col + 3] = v.w;
        }
        if (tid < 192) {
            int g = t0 - 32 + tid;
            xs[tid] = ((unsigned)g < (unsigned)T_LEN) ? x[(size_t)b * T_LEN + g] : 0.f;
        }
    }
    __syncthreads();

    // ---------------- phase 1: in-block prep ----------------
    if (tid < 64) {
        // One thread per shapelet: EXACT R2 prep arithmetic (serial order).
        const int p = tid;
        float s1 = 0.f;
        for (int l = 0; l < 64; ++l) s1 += Sraw[p][l];
        float mu = s1 * (1.f / 64.f);
        float sq = 0.f;
        for (int l = 0; l < 64; ++l) { float d = Sraw[p][l] - mu; sq = fmaf(d, d, sq); }
        float sd  = fmaxf(sqrtf(sq * (1.f / 64.f)), EPSF);
        float inv = 1.f / sd;
        float ssum = 0.f, ss2 = 0.f;
        for (int l2 = 0; l2 < 32; ++l2) {
            unsigned pk_h, pk_l;
            {   // element 2*l2 (low half)
                float v = Sraw[p][2 * l2];
                float s = (v - mu) * inv;
                unsigned ub = __float_as_uint(s);
                float hi = __uint_as_float(ub & 0xFFFF0000u);
                float lo = s - hi;
                unsigned lb = __float_as_uint(lo) & 0xFFFF0000u;
                pk_h = ub >> 16;
                pk_l = lb >> 16;
                float eff = hi + __uint_as_float(lb);
                ssum += eff;
                ss2  = fmaf(eff, eff, ss2);
            }
            {   // element 2*l2+1 (high half)
                float v = Sraw[p][2 * l2 + 1];
                float s = (v - mu) * inv;
                unsigned ub = __float_as_uint(s);
                float hi = __uint_as_float(ub & 0xFFFF0000u);
                float lo = s - hi;
                unsigned lb = __float_as_uint(lo) & 0xFFFF0000u;
                pk_h |= (ub & 0xFFFF0000u);
                pk_l |= lb;
                float eff = hi + __uint_as_float(lb);
                ssum += eff;
                ss2  = fmaf(eff, eff, ss2);
            }
            *(unsigned*)&Bhi[p][2 * l2] = pk_h;    // 4B-aligned (144|4, 4*l2)
            *(unsigned*)&Blo[p][2 * l2] = pk_l;
        }
        lsum[p] = ssum;
        ls2[p]  = ss2;
    } else if (tid < 192) {
        // per-row window stats (verbatim R2 math)
        const int r = tid - 64;
        float s1 = 0.f, sq = 0.f;
#pragma unroll
        for (int l = 0; l < 64; ++l) {
            float v = xs[r + l];
            s1 += v; sq = fmaf(v, v, sq);
        }
        float mu  = s1 * (1.f / 64.f);
        float var = fmaxf(sq * (1.f / 64.f) - mu * mu, 0.f);
        float sd  = fmaxf(sqrtf(var), EPSF);
        float inv = 1.f / sd;
        lmu[r]  = mu;
        linv[r] = inv;
        lw2[r]  = 64.f * var * inv * inv;
    }
    __syncthreads();

    // ---------------- phase 2: MFMA main (verbatim R2) ----------------
    // B-operand layout: lane holds B[k = quad*8+j + 32*h][col = lane&15]
    short8 Bh[4][2], Bl[4][2];
#pragma unroll
    for (int pt = 0; pt < 4; ++pt)
#pragma unroll
        for (int h = 0; h < 2; ++h) {
            Bh[pt][h] = *(const short8*)&Bhi[pt * 16 + n][h * 32 + (quad << 3)];
            Bl[pt][h] = *(const short8*)&Blo[pt * 16 + n][h * 32 + (quad << 3)];
        }

#pragma unroll
    for (int u = 0; u < 2; ++u) {
        // A fragments: A[m][k] = xs[u*64 + wave*16 + m + k]
        // A-operand layout: lane holds A[m = lane&15][k = quad*8+j + 32*h]
        const int abase = (u << 6) + (wave << 4) + n + (quad << 3);
        short8 Ah[2], Al[2];
#pragma unroll
        for (int h = 0; h < 2; ++h) {
#pragma unroll
            for (int j = 0; j < 8; ++j) {
                float v = xs[abase + h * 32 + j];
                unsigned ub = __float_as_uint(v);
                unsigned hb = ub & 0xFFFF0000u;
                float lo = v - __uint_as_float(hb);
                Ah[h][j] = (short)(ub >> 16);
                Al[h][j] = (short)(__float_as_uint(lo) >> 16);
            }
        }

        float4v acc[4];
#pragma unroll
        for (int pt = 0; pt < 4; ++pt) {
            float4v a = {0.f, 0.f, 0.f, 0.f};
#pragma unroll
            for (int h = 0; h < 2; ++h) {
                a = __builtin_amdgcn_mfma_f32_16x16x32_bf16(Ah[h], Bh[pt][h], a, 0, 0, 0);
                a = __builtin_amdgcn_mfma_f32_16x16x32_bf16(Ah[h], Bl[pt][h], a, 0, 0, 0);
                a = __builtin_amdgcn_mfma_f32_16x16x32_bf16(Al[h], Bh[pt][h], a, 0, 0, 0);
            }
            acc[pt] = a;
        }

        // epilogue: fold window znorm, exp, store
        float sm[4], sv[4];
#pragma unroll
        for (int pt = 0; pt < 4; ++pt) { sm[pt] = lsum[pt * 16 + n]; sv[pt] = ls2[pt * 16 + n]; }
#pragma unroll
        for (int r = 0; r < 4; ++r) {
            // C/D layout: col = lane&15, row = quad*4 + r
            int tl = (u << 6) + (wave << 4) + (quad << 2) + r;
            int tg = t0 + tl;
            bool valid = (tg >= 32) && (tg <= 8160);
            float mu  = lmu[tl];
            float inv = linv[tl];
            float w2  = lw2[tl];
            float* orow = out + ((size_t)(b * T_LEN + tg) << 6);
#pragma unroll
            for (int pt = 0; pt < 4; ++pt) {
                float dot  = (acc[pt][r] - mu * sm[pt]) * inv;
                float dist = w2 + sv[pt] - 2.f * dot;
                orow[pt * 16 + n] = valid ? __expf(-dist) : 0.f;
            }
        }
    }
}

extern "C" void kernel_launch(void* const* d_in, const int* in_sizes, int n_in,
                              void* d_out, int out_size, void* d_ws, size_t ws_size,
                              hipStream_t stream) {
    const float* x  = (const float*)d_in[0];   // (32, 8192, 1)
    const float* sh = (const float*)d_in[1];   // (64, 1, 64)
    float* out = (float*)d_out;                // (32, 8192, 64)

    shapelet_fused<<<32 * 64, 256, 0, stream>>>(x, sh, out);
}